// Round 5
// baseline (209.152 us; speedup 1.0000x reference)
//
#include <hip/hip_runtime.h>
#include <hip/hip_cooperative_groups.h>
#include <math.h>

// Problem constants: IMG_SIZE=1024, B=64, G=128, A=3, N=1280, stride=8
#define NBOX     1280
#define BVAL     64
#define GVAL     128
#define NFLOAT   (BVAL * GVAL * GVAL * 15)   // 15,728,640 floats = 62.9 MB
#define NVEC     (NFLOAT / 4)                // 3,932,160 float4
#define SPAN_V4  4096                        // float4 per sweep block (64 KB span)
#define NSWEEP   (NVEC / SPAN_V4)            // 960 exactly
#define NBLK     (NSWEEP + 1)                // + 1 box block

namespace cg = cooperative_groups;

__device__ __forceinline__ float softplus_f(float z) {
    return fmaxf(z, 0.f) + __logf(1.f + __expf(-fabsf(z)));
}

// Shared body: blockIdx 0 = target build + dedup + gather-adjust (verified exact);
// blockIdx 1..960 = noobj sweep, single-generation register streaming (16 float4
// loads/thread up front, 64 KB span/block, ~3.75 blocks/CU all co-resident).
// R4 post-mortem: dur_us is insensitive to >12 µs of profiled yolo improvement —
// the timed iteration is dominated by harness dispatches (41.5 µs 256 MiB poison
// fill + restore copies). R5: delete the one dispatch we still own — fuse the
// final reduce via cooperative grid sync (one fewer graph node + kernel).
__device__ __forceinline__ float yolo_body(
    const float* __restrict__ yp,
    const float* __restrict__ gbox,
    const float* __restrict__ anch,
    const int*   __restrict__ bidx)
{
    __shared__ int skey[NBOX];   // box keys (block 0 only)
    __shared__ int scnt[BVAL];   // per-batch counts; scnt[0] reused for maxseg

    const int t = threadIdx.x;
    float acc = 0.f;

    if (blockIdx.x == 0) {
        if (t < BVAL) scnt[t] = 0;
        __syncthreads();

        // ---- phase 1: per-box key (kept in regs too) + batch histogram ----
        int mykey[5];
        #pragma unroll
        for (int k = 0; k < 5; k++) {
            int n = t + k * 256;                     // 5*256 == NBOX exactly
            float4 g = ((const float4*)gbox)[n];
            float gx = g.x * 0.125f;
            float gy = g.y * 0.125f;
            float gw = g.z * 0.125f;
            float gh = g.w * 0.125f;
            int gi = (int)gx, gj = (int)gy;
            int best = 0; float bestr = -1.f;
            #pragma unroll
            for (int a = 0; a < 3; a++) {
                float aw = anch[a * 2 + 0] * 0.125f;
                float ah = anch[a * 2 + 1] * 0.125f;
                float inter = fminf(aw, gw) * fminf(ah, gh);
                float uni   = aw * ah + gw * gh - inter;
                float r     = inter / uni;
                if (r > bestr) { bestr = r; best = a; }   // first-wins ties, like argmax
            }
            int b = bidx[n];
            int key = ((b * 3 + best) * 128 + gj) * 128 + gi;
            skey[n]  = key;
            mykey[k] = key;
            atomicAdd(&scnt[b], 1);                  // LDS atomic — cheap
        }
        __syncthreads();

        // ---- maxseg = max boxes in any batch (bound on duplicate-pair distance) ----
        if (t < 64) {
            int v = scnt[t];
            #pragma unroll
            for (int off = 32; off > 0; off >>= 1) v = max(v, __shfl_down(v, off, 64));
            if (t == 0) scnt[0] = v;
        }
        __syncthreads();
        const int maxseg = scnt[0];

        // ---- phase 2: dedup, last-write-wins; fixed trip count, branch-free ----
        bool win[5];
        #pragma unroll
        for (int k = 0; k < 5; k++) win[k] = true;
        for (int d = 1; d <= maxseg; d++) {
            #pragma unroll
            for (int k = 0; k < 5; k++) {
                int m2 = t + k * 256 + d;
                int mc = m2 < NBOX ? m2 : NBOX - 1;       // clamp (guard result below)
                int other = skey[mc];
                if (m2 < NBOX && other == mykey[k]) win[k] = false;
            }
        }

        // ---- phase 3: winners recompute targets + gather pred + accumulate ----
        #pragma unroll
        for (int k = 0; k < 5; k++) {
            if (!win[k]) continue;
            int n = t + k * 256;
            float4 g = ((const float4*)gbox)[n];
            float gx = g.x * 0.125f;
            float gy = g.y * 0.125f;
            float gw = g.z * 0.125f;
            float gh = g.w * 0.125f;
            int gi = (int)gx, gj = (int)gy;
            int best = 0; float bestr = -1.f, baw = 1.f, bah = 1.f;
            #pragma unroll
            for (int a = 0; a < 3; a++) {
                float aw = anch[a * 2 + 0] * 0.125f;
                float ah = anch[a * 2 + 1] * 0.125f;
                float inter = fminf(aw, gw) * fminf(ah, gh);
                float uni   = aw * ah + gw * gh - inter;
                float r     = inter / uni;
                if (r > bestr) { bestr = r; best = a; baw = aw; bah = ah; }
            }
            float tx = gx - (float)gi;
            float ty = gy - (float)gj;
            float tw = __logf(gw / baw);
            float th = __logf(gh / bah);
            int b = bidx[n];
            long base = ((((long)b * GVAL + gj) * GVAL) + gi) * 15 + best * 5;
            float conf = yp[base + 0];
            float px = 1.f / (1.f + __expf(-yp[base + 1]));
            float py = 1.f / (1.f + __expf(-yp[base + 2]));
            float pw = yp[base + 3];
            float ph = yp[base + 4];
            float dx = px - tx, dy = py - ty, dw = pw - tw, dh = ph - th;
            float lp = __logf(1.f + __expf(-fabsf(conf)));
            float sp_pos = fmaxf( conf, 0.f) + lp;   // softplus(conf)
            float sp_neg = fmaxf(-conf, 0.f) + lp;   // softplus(-conf)
            acc += 5.f * (dx * dx + dy * dy + dw * dw + dh * dh)
                 + sp_neg - 0.5f * sp_pos;           // obj minus over-counted noobj
        }
    } else {
        // ---- noobj sweep: 0.5 * sum softplus(words ≡ 0 mod 5) ----
        // 16 coalesced float4 loads issued up front (all in flight), then fold.
        // Conf logits are every 5th word; float4 m holds one conf at component
        // j = m % 5 (none when j==4); k-step 256 ≡ 1 (mod 5) so j advances by +1.
        const float4* src = (const float4*)yp + (long)(blockIdx.x - 1) * SPAN_V4;
        float4 v[16];
        #pragma unroll
        for (int k = 0; k < 16; k++) v[k] = src[t + k * 256];

        int j = ((blockIdx.x - 1) * SPAN_V4 + t) % 5;
        float lacc = 0.f;
        #pragma unroll
        for (int k = 0; k < 16; k++) {
            float c  = (j == 0) ? v[k].x
                     : (j == 1) ? v[k].y
                     : (j == 2) ? v[k].z
                     :            v[k].w;
            float sp = softplus_f(c);
            lacc += (j < 4) ? sp : 0.f;              // j==4: float4 holds no conf
            j = (j == 4) ? 0 : j + 1;
        }
        acc = 0.5f * lacc;
    }
    return acc;
}

__device__ __forceinline__ float block_reduce(float acc) {
    __shared__ float swave[4];
    const int t = threadIdx.x;
    #pragma unroll
    for (int off = 32; off > 0; off >>= 1) acc += __shfl_down(acc, off, 64);
    int lane = t & 63, wid = t >> 6;
    if (lane == 0) swave[wid] = acc;
    __syncthreads();
    return swave[0] + swave[1] + swave[2] + swave[3];   // valid in all threads
}

// ---- fused: cooperative grid sync replaces the second dispatch ----
__global__ void __launch_bounds__(256) yolo_fused_kernel(
    const float* __restrict__ yp,
    const float* __restrict__ gbox,
    const float* __restrict__ anch,
    const int*   __restrict__ bidx,
    float*       __restrict__ part,
    float*       __restrict__ out)
{
    float acc = yolo_body(yp, gbox, anch, bidx);
    float bsum = block_reduce(acc);
    if (threadIdx.x == 0) part[blockIdx.x] = bsum;   // plain store, no atomics

    cg::this_grid().sync();                          // all 961 blocks co-resident

    if (blockIdx.x == 0) {
        const int t = threadIdx.x;
        float a2 = 0.f;
        for (int i = t; i < NBLK; i += 256) a2 += part[i];   // 4 iters, L2-hot
        float total = block_reduce(a2);
        if (t == 0) out[0] = total;   // overwrites 0xAA poison directly
    }
}

// ---- fallback pair (used only if cooperative launch is refused) ----
__global__ void __launch_bounds__(256) yolo_plain_kernel(
    const float* __restrict__ yp,
    const float* __restrict__ gbox,
    const float* __restrict__ anch,
    const int*   __restrict__ bidx,
    float*       __restrict__ part)
{
    float acc = yolo_body(yp, gbox, anch, bidx);
    float bsum = block_reduce(acc);
    if (threadIdx.x == 0) part[blockIdx.x] = bsum;
}

__global__ void __launch_bounds__(256) final_reduce_kernel(
    const float* __restrict__ part, float* __restrict__ out)
{
    const int t = threadIdx.x;
    float acc = 0.f;
    for (int i = t; i < NBLK; i += 256) acc += part[i];
    float total = block_reduce(acc);
    if (t == 0) out[0] = total;
}

extern "C" void kernel_launch(void* const* d_in, const int* in_sizes, int n_in,
                              void* d_out, int out_size, void* d_ws, size_t ws_size,
                              hipStream_t stream) {
    const float* yp   = (const float*)d_in[0];   // y_pred (B,G,G,15) fp32
    const float* gbox = (const float*)d_in[1];   // ground_bboxes (N,4) fp32
    const float* anch = (const float*)d_in[2];   // anchors (3,2) fp32
    const int*   bidx = (const int*)d_in[3];     // batch_idx (N,) int32
    float* part = (float*)d_ws;                  // NBLK partials (3844 B)
    float* outp = (float*)d_out;

    void* args[] = { (void*)&yp, (void*)&gbox, (void*)&anch, (void*)&bidx,
                     (void*)&part, (void*)&outp };
    hipError_t e = hipLaunchCooperativeKernel((const void*)yolo_fused_kernel,
                                              dim3(NBLK), dim3(256), args, 0, stream);
    if (e != hipSuccess) {
        // occupancy or capture refusal — fall back to the verified 2-kernel path
        yolo_plain_kernel<<<dim3(NBLK), dim3(256), 0, stream>>>(yp, gbox, anch, bidx, part);
        final_reduce_kernel<<<dim3(1), dim3(256), 0, stream>>>(part, outp);
    }
}

// Round 6
// 104.562 us; speedup vs baseline: 2.0003x; 2.0003x over previous
//
#include <hip/hip_runtime.h>
#include <math.h>

// Problem constants: IMG_SIZE=1024, B=64, G=128, A=3, N=1280, stride=8
#define NBOX     1280
#define BVAL     64
#define GVAL     128
#define NFLOAT   (BVAL * GVAL * GVAL * 15)   // 15,728,640 floats = 62.9 MB
#define NVEC     (NFLOAT / 4)                // 3,932,160 float4
#define SPAN_V4  4096                        // float4 per sweep block (64 KB span)
#define NSWEEP   (NVEC / SPAN_V4)            // 960 exactly
#define NBLK     (NSWEEP + 1)                // + 1 box block

typedef unsigned long long u64;
#define TAG 0x5A17C0DEull                    // publish tag (poison 0xAAAAAAAA can't spoof)

__device__ __forceinline__ float softplus_f(float z) {
    return fmaxf(z, 0.f) + __logf(1.f + __expf(-fabsf(z)));
}

// R5 post-mortem: cooperative grid.sync() collapsed the kernel 42 -> 104-117 µs
// (hbm 290 GB/s): per-block device-release fences (L2 writeback/inv across 8
// XCDs) + ~3800 waves spinning one coherent line, concurrent with straggler
// streaming. Reverted.
// R6: single dispatch WITHOUT grid sync — each sweep block publishes its partial
// as ONE agent-scope relaxed 64-bit atomic store (value packed with TAG in the
// same word: atomicity = visibility + payload, no fence, no L2 writeback storm,
// distinct addresses so no same-line serialization). Block 0 (resident from
// t=0; no dependency on later blocks -> no deadlock) polls the 960 slots with
// 4 waves and sums in EXACTLY final_reduce_kernel's order -> bit-identical.
//
// blockIdx 0       : target build + dedup (fixed-trip, branch-free) + gather-
//                    adjust, then polling reduce of all partials.
// blockIdx 1..960  : noobj sweep, single-generation register streaming
//                    (16 float4 loads/thread up front, 64 KB span/block,
//                    ~3.75 blocks/CU all co-resident -> no block churn).
__device__ __forceinline__ float yolo_body(
    const float* __restrict__ yp,
    const float* __restrict__ gbox,
    const float* __restrict__ anch,
    const int*   __restrict__ bidx)
{
    __shared__ int skey[NBOX];   // box keys (block 0 only)
    __shared__ int scnt[BVAL];   // per-batch counts; scnt[0] reused for maxseg

    const int t = threadIdx.x;
    float acc = 0.f;

    if (blockIdx.x == 0) {
        if (t < BVAL) scnt[t] = 0;
        __syncthreads();

        // ---- phase 1: per-box key (kept in regs too) + batch histogram ----
        int mykey[5];
        #pragma unroll
        for (int k = 0; k < 5; k++) {
            int n = t + k * 256;                     // 5*256 == NBOX exactly
            float4 g = ((const float4*)gbox)[n];
            float gx = g.x * 0.125f;
            float gy = g.y * 0.125f;
            float gw = g.z * 0.125f;
            float gh = g.w * 0.125f;
            int gi = (int)gx, gj = (int)gy;
            int best = 0; float bestr = -1.f;
            #pragma unroll
            for (int a = 0; a < 3; a++) {
                float aw = anch[a * 2 + 0] * 0.125f;
                float ah = anch[a * 2 + 1] * 0.125f;
                float inter = fminf(aw, gw) * fminf(ah, gh);
                float uni   = aw * ah + gw * gh - inter;
                float r     = inter / uni;
                if (r > bestr) { bestr = r; best = a; }   // first-wins ties, like argmax
            }
            int b = bidx[n];
            int key = ((b * 3 + best) * 128 + gj) * 128 + gi;
            skey[n]  = key;
            mykey[k] = key;
            atomicAdd(&scnt[b], 1);                  // LDS atomic — cheap
        }
        __syncthreads();

        // ---- maxseg = max boxes in any batch (bound on duplicate-pair distance) ----
        if (t < 64) {
            int v = scnt[t];
            #pragma unroll
            for (int off = 32; off > 0; off >>= 1) v = max(v, __shfl_down(v, off, 64));
            if (t == 0) scnt[0] = v;
        }
        __syncthreads();
        const int maxseg = scnt[0];

        // ---- phase 2: dedup, last-write-wins; fixed trip count, branch-free ----
        bool win[5];
        #pragma unroll
        for (int k = 0; k < 5; k++) win[k] = true;
        for (int d = 1; d <= maxseg; d++) {
            #pragma unroll
            for (int k = 0; k < 5; k++) {
                int m2 = t + k * 256 + d;
                int mc = m2 < NBOX ? m2 : NBOX - 1;       // clamp (guard result below)
                int other = skey[mc];
                if (m2 < NBOX && other == mykey[k]) win[k] = false;
            }
        }

        // ---- phase 3: winners recompute targets + gather pred + accumulate ----
        #pragma unroll
        for (int k = 0; k < 5; k++) {
            if (!win[k]) continue;
            int n = t + k * 256;
            float4 g = ((const float4*)gbox)[n];
            float gx = g.x * 0.125f;
            float gy = g.y * 0.125f;
            float gw = g.z * 0.125f;
            float gh = g.w * 0.125f;
            int gi = (int)gx, gj = (int)gy;
            int best = 0; float bestr = -1.f, baw = 1.f, bah = 1.f;
            #pragma unroll
            for (int a = 0; a < 3; a++) {
                float aw = anch[a * 2 + 0] * 0.125f;
                float ah = anch[a * 2 + 1] * 0.125f;
                float inter = fminf(aw, gw) * fminf(ah, gh);
                float uni   = aw * ah + gw * gh - inter;
                float r     = inter / uni;
                if (r > bestr) { bestr = r; best = a; baw = aw; bah = ah; }
            }
            float tx = gx - (float)gi;
            float ty = gy - (float)gj;
            float tw = __logf(gw / baw);
            float th = __logf(gh / bah);
            int b = bidx[n];
            long base = ((((long)b * GVAL + gj) * GVAL) + gi) * 15 + best * 5;
            float conf = yp[base + 0];
            float px = 1.f / (1.f + __expf(-yp[base + 1]));
            float py = 1.f / (1.f + __expf(-yp[base + 2]));
            float pw = yp[base + 3];
            float ph = yp[base + 4];
            float dx = px - tx, dy = py - ty, dw = pw - tw, dh = ph - th;
            float lp = __logf(1.f + __expf(-fabsf(conf)));
            float sp_pos = fmaxf( conf, 0.f) + lp;   // softplus(conf)
            float sp_neg = fmaxf(-conf, 0.f) + lp;   // softplus(-conf)
            acc += 5.f * (dx * dx + dy * dy + dw * dw + dh * dh)
                 + sp_neg - 0.5f * sp_pos;           // obj minus over-counted noobj
        }
    } else {
        // ---- noobj sweep: 0.5 * sum softplus(words ≡ 0 mod 5) ----
        // 16 coalesced float4 loads issued up front (all in flight), then fold.
        // Conf logits are every 5th word; float4 m holds one conf at component
        // j = m % 5 (none when j==4); k-step 256 ≡ 1 (mod 5) so j advances by +1.
        const float4* src = (const float4*)yp + (long)(blockIdx.x - 1) * SPAN_V4;
        float4 v[16];
        #pragma unroll
        for (int k = 0; k < 16; k++) v[k] = src[t + k * 256];

        int j = ((blockIdx.x - 1) * SPAN_V4 + t) % 5;
        float lacc = 0.f;
        #pragma unroll
        for (int k = 0; k < 16; k++) {
            float c  = (j == 0) ? v[k].x
                     : (j == 1) ? v[k].y
                     : (j == 2) ? v[k].z
                     :            v[k].w;
            float sp = softplus_f(c);
            lacc += (j < 4) ? sp : 0.f;              // j==4: float4 holds no conf
            j = (j == 4) ? 0 : j + 1;
        }
        acc = 0.5f * lacc;
    }
    return acc;
}

__device__ __forceinline__ float block_reduce(float acc) {
    __shared__ float swave[4];
    const int t = threadIdx.x;
    __syncthreads();                                 // guard swave reuse across calls
    #pragma unroll
    for (int off = 32; off > 0; off >>= 1) acc += __shfl_down(acc, off, 64);
    int lane = t & 63, wid = t >> 6;
    if (lane == 0) swave[wid] = acc;
    __syncthreads();
    return swave[0] + swave[1] + swave[2] + swave[3];   // valid in all threads
}

__global__ void __launch_bounds__(256) yolo_fused_kernel(
    const float* __restrict__ yp,
    const float* __restrict__ gbox,
    const float* __restrict__ anch,
    const int*   __restrict__ bidx,
    u64*         __restrict__ slot,
    float*       __restrict__ out)
{
    const int t = threadIdx.x;
    float acc  = yolo_body(yp, gbox, anch, bidx);
    float bsum = block_reduce(acc);

    if (blockIdx.x != 0) {
        if (t == 0) {
            u64 p = ((u64)TAG << 32) | (u64)__float_as_uint(bsum);
            __hip_atomic_store(&slot[blockIdx.x], p,
                               __ATOMIC_RELAXED, __HIP_MEMORY_SCOPE_AGENT);
        }
        return;
    }

    // ---- block 0: polling reduce, summation order IDENTICAL to the old
    // final_reduce_kernel (thread t: i = t, t+256, t+512, t+768; i==0 is our
    // own bsum) -> bit-exact result. 4 waves polling L3 slots: gentle.
    float a2 = 0.f;
    for (int i = t; i < NBLK; i += 256) {
        float term;
        if (i == 0) {
            term = bsum;
        } else {
            u64 v = __hip_atomic_load(&slot[i], __ATOMIC_RELAXED,
                                      __HIP_MEMORY_SCOPE_AGENT);
            while ((unsigned)(v >> 32) != (unsigned)TAG) {
                __builtin_amdgcn_s_sleep(8);
                v = __hip_atomic_load(&slot[i], __ATOMIC_RELAXED,
                                      __HIP_MEMORY_SCOPE_AGENT);
            }
            term = __uint_as_float((unsigned)v);
        }
        a2 += term;
    }
    float total = block_reduce(a2);
    if (t == 0) out[0] = total;   // plain store overwrites the 0xAA poison
}

extern "C" void kernel_launch(void* const* d_in, const int* in_sizes, int n_in,
                              void* d_out, int out_size, void* d_ws, size_t ws_size,
                              hipStream_t stream) {
    const float* yp   = (const float*)d_in[0];   // y_pred (B,G,G,15) fp32
    const float* gbox = (const float*)d_in[1];   // ground_bboxes (N,4) fp32
    const float* anch = (const float*)d_in[2];   // anchors (3,2) fp32
    const int*   bidx = (const int*)d_in[3];     // batch_idx (N,) int32
    u64*  slot = (u64*)d_ws;                     // NBLK publish slots (7688 B)
    float* outp = (float*)d_out;

    yolo_fused_kernel<<<dim3(NBLK), dim3(256), 0, stream>>>(yp, gbox, anch, bidx,
                                                            slot, outp);
}